// Round 1
// baseline (87488.123 us; speedup 1.0000x reference)
//
#include <hip/hip_runtime.h>
#include <cstdint>

#define TENC 2048
#define TDEC 256
#define BSZ  128
#define HID  256
#define KEYD 128
#define VALD 128
#define H1D  512
#define N1   2048   // 4*H1D
#define K1   896    // HID + VALD + H1D
#define N2   512    // 4*KEYD
#define K2   640    // H1D + KEYD
#define VOC  1000
#define NPAD 1024

// ---- workspace layout (float offsets) ----
#define OFF_WT1   0            // 896*2048  k-major [k][n], n = gate*512+j
#define OFF_WT2   1835008      // 640*512
#define OFF_WLT   2162688      // 256*1024 (n padded to 1024)
#define OFF_B1    2424832      // 2048
#define OFF_B2    2426880      // 512
#define OFF_X1U   2427392      // 128*896  [emb(256) | ctx(128) | h1(512)]
#define OFF_C1    2542080      // 128*512
#define OFF_H2    2607616      // 128*128
#define OFF_C2    2624000      // 128*128
#define OFF_CTX   2640384      // 128*128
#define OFF_P1    2656768      // 4*128*2048 k-split partials LSTM1
#define OFF_P2    3705344      // 4*128*512  k-split partials LSTM2
// total 3967488 floats = 15.9 MB

#define PREP_ELEMS 2656768     // everything before P1 gets initialized
// 2656768 / 256 = 10378 blocks exactly

__device__ __forceinline__ float sigf(float x)   { return 1.0f / (1.0f + __expf(-x)); }
__device__ __forceinline__ float tanhf2(float x) { return 1.0f - 2.0f / (__expf(2.0f * x) + 1.0f); }

// One-time: transpose weights to k-major, fuse biases, init states, build x1u for t=0.
__global__ __launch_bounds__(256) void prep_kernel(
    const float* __restrict__ Wih1, const float* __restrict__ Whh1,
    const float* __restrict__ bih1, const float* __restrict__ bhh1,
    const float* __restrict__ Wih2, const float* __restrict__ Whh2,
    const float* __restrict__ bih2, const float* __restrict__ bhh2,
    const float* __restrict__ Wlin, const float* __restrict__ emb,
    const int* __restrict__ text, float* __restrict__ ws)
{
    int i = blockIdx.x * 256 + threadIdx.x;
    if (i < 1835008) {                       // WT1[k][n]
        int k = i >> 11, n = i & 2047;
        ws[OFF_WT1 + i] = (k < 384) ? Wih1[n * 384 + k] : Whh1[n * 512 + (k - 384)];
        return;
    }
    i -= 1835008;
    if (i < 327680) {                        // WT2[k][n]
        int k = i >> 9, n = i & 511;
        ws[OFF_WT2 + i] = (k < 512) ? Wih2[n * 512 + k] : Whh2[n * 128 + (k - 512)];
        return;
    }
    i -= 327680;
    if (i < 262144) {                        // WlinT[k][n], n padded to 1024
        int k = i >> 10, n = i & 1023;
        ws[OFF_WLT + i] = (n < VOC) ? Wlin[n * 256 + k] : 0.0f;
        return;
    }
    i -= 262144;
    if (i < 2048) { ws[OFF_B1 + i] = bih1[i] + bhh1[i]; return; }
    i -= 2048;
    if (i < 512)  { ws[OFF_B2 + i] = bih2[i] + bhh2[i]; return; }
    i -= 512;
    if (i < 114688) {                        // x1u for t=0: emb(text[:,0]) | 0 | 0
        int b = i / K1, k = i % K1;
        float v = 0.0f;
        if (k < HID) v = emb[text[b * TDEC] * HID + k];
        ws[OFF_X1U + i] = v;
        return;
    }
    i -= 114688;
    if (i < 65536) { ws[OFF_C1 + i] = 0.0f; return; }
    i -= 65536;
    if (i < 16384) { ws[OFF_H2 + i] = 0.0f; return; }
    i -= 16384;
    if (i < 16384) { ws[OFF_C2 + i] = 0.0f; return; }
    i -= 16384;
    ws[OFF_CTX + i] = 0.0f;                  // last 16384
}

// LSTM1 gates partial GEMM: M=128(b), N=2048, K=896, K-split 4.
// Thread: 4b x 4n tile; lane-consecutive n4 -> coalesced float4 weight loads.
__global__ __launch_bounds__(256) void l1A_kernel(float* __restrict__ ws)
{
    const float* WT1 = ws + OFF_WT1;
    const float* x1u = ws + OFF_X1U;
    float* p1 = ws + OFF_P1;
    int T  = blockIdx.x * 256 + threadIdx.x;   // 65536
    int n4 = T & 511;
    int bq = (T >> 9) & 31;
    int s  = T >> 14;                           // 0..3
    const float* xb = x1u + bq * 4 * K1;
    float4 a0 = {0,0,0,0}, a1 = a0, a2 = a0, a3 = a0;
    int k0 = s * 224;
    for (int k = k0; k < k0 + 224; ++k) {
        float4 w = ((const float4*)(WT1 + (size_t)k * N1))[n4];
        float x0 = xb[k], x1v = xb[K1 + k], x2v = xb[2 * K1 + k], x3v = xb[3 * K1 + k];
        a0.x += x0 * w.x; a0.y += x0 * w.y; a0.z += x0 * w.z; a0.w += x0 * w.w;
        a1.x += x1v * w.x; a1.y += x1v * w.y; a1.z += x1v * w.z; a1.w += x1v * w.w;
        a2.x += x2v * w.x; a2.y += x2v * w.y; a2.z += x2v * w.z; a2.w += x2v * w.w;
        a3.x += x3v * w.x; a3.y += x3v * w.y; a3.z += x3v * w.z; a3.w += x3v * w.w;
    }
    size_t base = ((size_t)(s * BSZ + bq * 4)) * N1 + n4 * 4;
    *(float4*)(p1 + base)          = a0;
    *(float4*)(p1 + base + N1)     = a1;
    *(float4*)(p1 + base + 2 * N1) = a2;
    *(float4*)(p1 + base + 3 * N1) = a3;
}

// LSTM1 cell: reduce 4 partials, elementwise, write c1 and h1 (into x1u).
__global__ __launch_bounds__(256) void l1B_kernel(float* __restrict__ ws)
{
    const float* p1 = ws + OFF_P1;
    const float* b1 = ws + OFF_B1;
    float* c1  = ws + OFF_C1;
    float* x1u = ws + OFF_X1U;
    int T = blockIdx.x * 256 + threadIdx.x;    // 65536
    int j = T & 511, b = T >> 9;
    float gi = b1[j], gf = b1[512 + j], gg = b1[1024 + j], go = b1[1536 + j];
    #pragma unroll
    for (int s = 0; s < 4; ++s) {
        const float* pp = p1 + (size_t)(s * BSZ + b) * N1;
        gi += pp[j]; gf += pp[512 + j]; gg += pp[1024 + j]; go += pp[1536 + j];
    }
    float c = sigf(gf) * c1[b * 512 + j] + sigf(gi) * tanhf2(gg);
    c1[b * 512 + j] = c;
    x1u[b * K1 + 384 + j] = sigf(go) * tanhf2(c);
}

// LSTM2 gates partial GEMM: M=128, N=512, K=640 ([h1|h2]), K-split 4.
__global__ __launch_bounds__(256) void l2A_kernel(float* __restrict__ ws)
{
    const float* WT2 = ws + OFF_WT2;
    const float* x1u = ws + OFF_X1U;
    const float* h2  = ws + OFF_H2;
    float* p2 = ws + OFF_P2;
    int T  = blockIdx.x * 256 + threadIdx.x;   // 16384
    int n4 = T & 127;
    int bq = (T >> 7) & 31;
    int s  = T >> 12;                           // 0..3
    const float* hb  = x1u + bq * 4 * K1 + 384; // h1 slice
    const float* h2b = h2 + bq * 4 * 128;
    float4 a0 = {0,0,0,0}, a1 = a0, a2 = a0, a3 = a0;
    int k0 = s * 160;
    for (int k = k0; k < k0 + 160; ++k) {
        float4 w = ((const float4*)(WT2 + (size_t)k * N2))[n4];
        float x0, x1v, x2v, x3v;
        if (k < 512) { x0 = hb[k];  x1v = hb[K1 + k];  x2v = hb[2 * K1 + k];  x3v = hb[3 * K1 + k]; }
        else { int kk = k - 512; x0 = h2b[kk]; x1v = h2b[128 + kk]; x2v = h2b[256 + kk]; x3v = h2b[384 + kk]; }
        a0.x += x0 * w.x; a0.y += x0 * w.y; a0.z += x0 * w.z; a0.w += x0 * w.w;
        a1.x += x1v * w.x; a1.y += x1v * w.y; a1.z += x1v * w.z; a1.w += x1v * w.w;
        a2.x += x2v * w.x; a2.y += x2v * w.y; a2.z += x2v * w.z; a2.w += x2v * w.w;
        a3.x += x3v * w.x; a3.y += x3v * w.y; a3.z += x3v * w.z; a3.w += x3v * w.w;
    }
    size_t base = ((size_t)(s * BSZ + bq * 4)) * N2 + n4 * 4;
    *(float4*)(p2 + base)          = a0;
    *(float4*)(p2 + base + N2)     = a1;
    *(float4*)(p2 + base + 2 * N2) = a2;
    *(float4*)(p2 + base + 3 * N2) = a3;
}

// Per-batch fused: LSTM2 cell + energy + softmax + ctx + next-step x1 staging.
// One WG per batch element (grid 128, block 512 = 8 waves).
__global__ __launch_bounds__(512) void attn_kernel(
    const float* __restrict__ keys, const float* __restrict__ values,
    const int* __restrict__ lens, const int* __restrict__ text,
    const float* __restrict__ emb, float* __restrict__ ws, int t)
{
    __shared__ float s_h2[128];
    __shared__ float s_e[TENC];
    __shared__ float s_r[512];
    __shared__ float s_cp[1024];
    const float* p2 = ws + OFF_P2;
    const float* b2 = ws + OFF_B2;
    float* c2  = ws + OFF_C2;
    float* h2  = ws + OFF_H2;
    float* ctx = ws + OFF_CTX;
    float* x1u = ws + OFF_X1U;
    int b = blockIdx.x, tid = threadIdx.x;

    // LSTM2 cell update (fold)
    if (tid < 128) {
        int j = tid;
        float gi = b2[j], gf = b2[128 + j], gg = b2[256 + j], go = b2[384 + j];
        #pragma unroll
        for (int s = 0; s < 4; ++s) {
            const float* pp = p2 + (size_t)(s * BSZ + b) * N2;
            gi += pp[j]; gf += pp[128 + j]; gg += pp[256 + j]; go += pp[384 + j];
        }
        float c = sigf(gf) * c2[b * 128 + j] + sigf(gi) * tanhf2(gg);
        c2[b * 128 + j] = c;
        float h = sigf(go) * tanhf2(c);
        h2[b * 128 + j] = h;
        s_h2[j] = h;
    }
    __syncthreads();

    int wave = tid >> 6, lane = tid & 63;
    int lb = lens[b];
    float hx = s_h2[lane * 2], hy = s_h2[lane * 2 + 1];
    // energy: wave per t-row, 64 lanes x float2 = full 512B coalesced row
    for (int tt = wave; tt < TENC; tt += 8) {
        float2 kv = *(const float2*)(keys + (size_t)tt * 16384 + b * 128 + lane * 2);
        float p = kv.x * hx + kv.y * hy;
        p += __shfl_down(p, 32);
        p += __shfl_down(p, 16);
        p += __shfl_down(p, 8);
        p += __shfl_down(p, 4);
        p += __shfl_down(p, 2);
        p += __shfl_down(p, 1);
        if (lane == 0) s_e[tt] = (tt >= lb) ? -1e9f : p;
    }
    __syncthreads();

    // softmax over 2048
    float m = -3.4e38f;
    for (int i = tid; i < TENC; i += 512) m = fmaxf(m, s_e[i]);
    s_r[tid] = m; __syncthreads();
    for (int st = 256; st > 0; st >>= 1) {
        if (tid < st) s_r[tid] = fmaxf(s_r[tid], s_r[tid + st]);
        __syncthreads();
    }
    m = s_r[0]; __syncthreads();
    float sum = 0.0f;
    for (int i = tid; i < TENC; i += 512) { float e = __expf(s_e[i] - m); s_e[i] = e; sum += e; }
    s_r[tid] = sum; __syncthreads();
    for (int st = 256; st > 0; st >>= 1) {
        if (tid < st) s_r[tid] += s_r[tid + st];
        __syncthreads();
    }
    float inv = 1.0f / s_r[0];

    // ctx: wave per t-row of values, coalesced
    float ax = 0.0f, ay = 0.0f;
    for (int tt = wave; tt < TENC; tt += 8) {
        float2 vv = *(const float2*)(values + (size_t)tt * 16384 + b * 128 + lane * 2);
        float a = s_e[tt];
        ax += a * vv.x; ay += a * vv.y;
    }
    s_cp[wave * 128 + lane * 2]     = ax;
    s_cp[wave * 128 + lane * 2 + 1] = ay;
    __syncthreads();
    if (tid < 128) {
        float c_ = 0.0f;
        #pragma unroll
        for (int w = 0; w < 8; ++w) c_ += s_cp[w * 128 + tid];
        c_ *= inv;
        ctx[b * 128 + tid] = c_;
        x1u[b * K1 + HID + tid] = c_;          // ctx slice of next x1
    } else if (tid < 384 && (t + 1) < TDEC) {  // prefetch next-step embedding
        int k = tid - 128;
        x1u[b * K1 + k] = emb[text[b * TDEC + t + 1] * HID + k];
    }
}

// Output projection: [h2|ctx] @ WlinT + blin -> out[b][t][:]
__global__ __launch_bounds__(256) void pred_kernel(
    const float* __restrict__ ws, const float* __restrict__ blin,
    float* __restrict__ out, int t)
{
    const float* WlinT = ws + OFF_WLT;
    const float* h2  = ws + OFF_H2;
    const float* ctx = ws + OFF_CTX;
    int T = blockIdx.x * 256 + threadIdx.x;    // 32768
    int n = T & 1023, bq = T >> 10;            // bq 0..31
    if (n >= VOC) return;
    float bl = blin[n];
    float a0 = bl, a1 = bl, a2 = bl, a3 = bl;
    const float* xA = h2  + bq * 4 * 128;
    const float* xB = ctx + bq * 4 * 128;
    for (int k = 0; k < 128; ++k) {
        float w = WlinT[k * NPAD + n];
        a0 += xA[k] * w; a1 += xA[128 + k] * w; a2 += xA[256 + k] * w; a3 += xA[384 + k] * w;
    }
    for (int k = 0; k < 128; ++k) {
        float w = WlinT[(128 + k) * NPAD + n];
        a0 += xB[k] * w; a1 += xB[128 + k] * w; a2 += xB[256 + k] * w; a3 += xB[384 + k] * w;
    }
    size_t o = ((size_t)(bq * 4) * TDEC + t) * VOC + n;
    out[o]                        = a0;
    out[o + (size_t)TDEC * VOC]   = a1;
    out[o + 2 * (size_t)TDEC * VOC] = a2;
    out[o + 3 * (size_t)TDEC * VOC] = a3;
}

extern "C" void kernel_launch(void* const* d_in, const int* in_sizes, int n_in,
                              void* d_out, int out_size, void* d_ws, size_t ws_size,
                              hipStream_t stream)
{
    const float* keys   = (const float*)d_in[0];
    const float* values = (const float*)d_in[1];
    const int*   lens   = (const int*)d_in[2];
    const int*   text   = (const int*)d_in[3];
    const float* emb    = (const float*)d_in[4];
    const float* Wih1   = (const float*)d_in[5];
    const float* Whh1   = (const float*)d_in[6];
    const float* bih1   = (const float*)d_in[7];
    const float* bhh1   = (const float*)d_in[8];
    const float* Wih2   = (const float*)d_in[9];
    const float* Whh2   = (const float*)d_in[10];
    const float* bih2   = (const float*)d_in[11];
    const float* bhh2   = (const float*)d_in[12];
    const float* Wlin   = (const float*)d_in[13];
    const float* blin   = (const float*)d_in[14];
    float* ws  = (float*)d_ws;
    float* out = (float*)d_out;

    prep_kernel<<<PREP_ELEMS / 256, 256, 0, stream>>>(
        Wih1, Whh1, bih1, bhh1, Wih2, Whh2, bih2, bhh2, Wlin, emb, text, ws);

    for (int t = 0; t < TDEC; ++t) {
        l1A_kernel<<<256, 256, 0, stream>>>(ws);
        l1B_kernel<<<256, 256, 0, stream>>>(ws);
        l2A_kernel<<<64, 256, 0, stream>>>(ws);
        attn_kernel<<<128, 512, 0, stream>>>(keys, values, lens, text, emb, ws, t);
        pred_kernel<<<128, 256, 0, stream>>>(ws, blin, out, t);
    }
}

// Round 2
// 42103.467 us; speedup vs baseline: 2.0779x; 2.0779x over previous
//
#include <hip/hip_runtime.h>
#include <cstdint>

#define TENC 2048
#define TDEC 256
#define BSZ  128
#define HID  256
#define KEYD 128
#define VALD 128
#define H1D  512
#define N1   2048   // 4*H1D
#define K1   896    // HID + VALD + H1D
#define N2   512    // 4*KEYD
#define VOC  1000
#define NPAD 1024
#define NSPLIT 16   // attention t-splits (2048/128)

// ---- workspace layout (float offsets) ----
#define OFF_WT1   0            // 896*2048  k-major [k][n]
#define OFF_WT2   1835008      // 640*512
#define OFF_WLT   2162688      // 256*1024 (n padded to 1024)
#define OFF_B1    2424832      // 2048
#define OFF_B2    2426880      // 512
#define OFF_X1U   2427392      // 128*896  [emb(256) | ctx(128) | h1(512)]
#define OFF_C1    2542080      // 128*512
#define OFF_H2    2607616      // 128*128
#define OFF_C2    2624000      // 128*128
#define OFF_CTX   2640384      // 128*128
#define OFF_P1    2656768      // 8*128*2048 k-split partials LSTM1
#define OFF_P2    4753920      // 4*128*512  k-split partials LSTM2
#define OFF_AM    5016064      // 128*16 attn local max
#define OFF_AS    5018112      // 128*16 attn local expsum
#define OFF_AP    5020160      // 128*16*128 attn partial ctx
// total 5282304 floats = 21.1 MB

#define PREP_ELEMS 2656768

__device__ __forceinline__ float sigf(float x)   { return 1.0f / (1.0f + __expf(-x)); }
__device__ __forceinline__ float tanhf2(float x) { return 1.0f - 2.0f / (__expf(2.0f * x) + 1.0f); }

// One-time: transpose weights to k-major, fuse biases, init states, build x1u for t=0.
__global__ __launch_bounds__(256) void prep_kernel(
    const float* __restrict__ Wih1, const float* __restrict__ Whh1,
    const float* __restrict__ bih1, const float* __restrict__ bhh1,
    const float* __restrict__ Wih2, const float* __restrict__ Whh2,
    const float* __restrict__ bih2, const float* __restrict__ bhh2,
    const float* __restrict__ Wlin, const float* __restrict__ emb,
    const int* __restrict__ text, float* __restrict__ ws)
{
    int i = blockIdx.x * 256 + threadIdx.x;
    if (i < 1835008) {                       // WT1[k][n]
        int k = i >> 11, n = i & 2047;
        ws[OFF_WT1 + i] = (k < 384) ? Wih1[n * 384 + k] : Whh1[n * 512 + (k - 384)];
        return;
    }
    i -= 1835008;
    if (i < 327680) {                        // WT2[k][n]
        int k = i >> 9, n = i & 511;
        ws[OFF_WT2 + i] = (k < 512) ? Wih2[n * 512 + k] : Whh2[n * 128 + (k - 512)];
        return;
    }
    i -= 327680;
    if (i < 262144) {                        // WlinT[k][n], n padded to 1024
        int k = i >> 10, n = i & 1023;
        ws[OFF_WLT + i] = (n < VOC) ? Wlin[n * 256 + k] : 0.0f;
        return;
    }
    i -= 262144;
    if (i < 2048) { ws[OFF_B1 + i] = bih1[i] + bhh1[i]; return; }
    i -= 2048;
    if (i < 512)  { ws[OFF_B2 + i] = bih2[i] + bhh2[i]; return; }
    i -= 512;
    if (i < 114688) {                        // x1u for t=0: emb(text[:,0]) | 0 | 0
        int b = i / K1, k = i % K1;
        float v = 0.0f;
        if (k < HID) v = emb[text[b * TDEC] * HID + k];
        ws[OFF_X1U + i] = v;
        return;
    }
    i -= 114688;
    if (i < 65536) { ws[OFF_C1 + i] = 0.0f; return; }
    i -= 65536;
    if (i < 16384) { ws[OFF_H2 + i] = 0.0f; return; }
    i -= 16384;
    if (i < 16384) { ws[OFF_C2 + i] = 0.0f; return; }
    i -= 16384;
    ws[OFF_CTX + i] = 0.0f;
}

// LSTM1 gates partial GEMM: M=128(b), N=2048, K=896. b-tile 8, K-split 8.
// 65536 threads: n4(512) x bq(16) x s(8). Weight traffic 117 MB/step.
__global__ __launch_bounds__(256) void l1A_kernel(float* __restrict__ ws)
{
    const float* WT1 = ws + OFF_WT1;
    const float* x1u = ws + OFF_X1U;
    float* p1 = ws + OFF_P1;
    int T  = blockIdx.x * 256 + threadIdx.x;
    int n4 = T & 511;
    int r  = T >> 9;
    int bq = r & 15;     // batch group of 8
    int s  = r >> 4;     // k-split 0..7
    const float* xb = x1u + bq * 8 * K1;
    float4 a[8];
    #pragma unroll
    for (int i = 0; i < 8; ++i) a[i] = make_float4(0.f, 0.f, 0.f, 0.f);
    int k0 = s * 112;
    for (int k = k0; k < k0 + 112; ++k) {
        float4 w = ((const float4*)(WT1 + (size_t)k * N1))[n4];
        #pragma unroll
        for (int i = 0; i < 8; ++i) {
            float x = xb[i * K1 + k];
            a[i].x += x * w.x; a[i].y += x * w.y; a[i].z += x * w.z; a[i].w += x * w.w;
        }
    }
    #pragma unroll
    for (int i = 0; i < 8; ++i) {
        size_t base = ((size_t)(s * BSZ + bq * 8 + i)) * N1 + n4 * 4;
        *(float4*)(p1 + base) = a[i];
    }
}

// LSTM1 cell: reduce 8 partials, elementwise, write c1 and h1 (into x1u).
__global__ __launch_bounds__(256) void l1B_kernel(float* __restrict__ ws)
{
    const float* p1 = ws + OFF_P1;
    const float* b1 = ws + OFF_B1;
    float* c1  = ws + OFF_C1;
    float* x1u = ws + OFF_X1U;
    int T = blockIdx.x * 256 + threadIdx.x;    // 65536
    int j = T & 511, b = T >> 9;
    float gi = b1[j], gf = b1[512 + j], gg = b1[1024 + j], go = b1[1536 + j];
    #pragma unroll
    for (int s = 0; s < 8; ++s) {
        const float* pp = p1 + (size_t)(s * BSZ + b) * N1;
        gi += pp[j]; gf += pp[512 + j]; gg += pp[1024 + j]; go += pp[1536 + j];
    }
    float c = sigf(gf) * c1[b * 512 + j] + sigf(gi) * tanhf2(gg);
    c1[b * 512 + j] = c;
    x1u[b * K1 + 384 + j] = sigf(go) * tanhf2(c);
}

// LSTM2 gates partial GEMM: M=128, N=512, K=640 ([h1|h2]), K-split 4.
__global__ __launch_bounds__(256) void l2A_kernel(float* __restrict__ ws)
{
    const float* WT2 = ws + OFF_WT2;
    const float* x1u = ws + OFF_X1U;
    const float* h2  = ws + OFF_H2;
    float* p2 = ws + OFF_P2;
    int T  = blockIdx.x * 256 + threadIdx.x;   // 16384
    int n4 = T & 127;
    int bq = (T >> 7) & 31;
    int s  = T >> 12;
    const float* hb  = x1u + bq * 4 * K1 + 384;
    const float* h2b = h2 + bq * 4 * 128;
    float4 a0 = {0,0,0,0}, a1 = a0, a2 = a0, a3 = a0;
    int k0 = s * 160;
    for (int k = k0; k < k0 + 160; ++k) {
        float4 w = ((const float4*)(WT2 + (size_t)k * N2))[n4];
        float x0, x1v, x2v, x3v;
        if (k < 512) { x0 = hb[k];  x1v = hb[K1 + k];  x2v = hb[2 * K1 + k];  x3v = hb[3 * K1 + k]; }
        else { int kk = k - 512; x0 = h2b[kk]; x1v = h2b[128 + kk]; x2v = h2b[256 + kk]; x3v = h2b[384 + kk]; }
        a0.x += x0 * w.x; a0.y += x0 * w.y; a0.z += x0 * w.z; a0.w += x0 * w.w;
        a1.x += x1v * w.x; a1.y += x1v * w.y; a1.z += x1v * w.z; a1.w += x1v * w.w;
        a2.x += x2v * w.x; a2.y += x2v * w.y; a2.z += x2v * w.z; a2.w += x2v * w.w;
        a3.x += x3v * w.x; a3.y += x3v * w.y; a3.z += x3v * w.z; a3.w += x3v * w.w;
    }
    size_t base = ((size_t)(s * BSZ + bq * 4)) * N2 + n4 * 4;
    *(float4*)(p2 + base)          = a0;
    *(float4*)(p2 + base + N2)     = a1;
    *(float4*)(p2 + base + 2 * N2) = a2;
    *(float4*)(p2 + base + 3 * N2) = a3;
}

// LSTM2 cell: reduce 4 partials, write c2, h2.
__global__ __launch_bounds__(256) void l2B_kernel(float* __restrict__ ws)
{
    const float* p2 = ws + OFF_P2;
    const float* b2 = ws + OFF_B2;
    float* c2 = ws + OFF_C2;
    float* h2 = ws + OFF_H2;
    int T = blockIdx.x * 256 + threadIdx.x;    // 16384
    int j = T & 127, b = T >> 7;
    float gi = b2[j], gf = b2[128 + j], gg = b2[256 + j], go = b2[384 + j];
    #pragma unroll
    for (int s = 0; s < 4; ++s) {
        const float* pp = p2 + (size_t)(s * BSZ + b) * N2;
        gi += pp[j]; gf += pp[128 + j]; gg += pp[256 + j]; go += pp[384 + j];
    }
    float c = sigf(gf) * c2[b * 128 + j] + sigf(gi) * tanhf2(gg);
    c2[b * 128 + j] = c;
    h2[b * 128 + j] = sigf(go) * tanhf2(c);
}

// Attention pass 1 (flash-style): grid (NSPLIT, B), block 256 (4 waves).
// Each block: 128 enc rows for one b -> local max m, expsum s, partial ctx.
__global__ __launch_bounds__(256) void attn1_kernel(
    const float* __restrict__ keys, const float* __restrict__ values,
    const int* __restrict__ lens, float* __restrict__ ws)
{
    __shared__ float s_h2[128];
    __shared__ float s_e[128];
    __shared__ float s_m[1];
    __shared__ float s_cp[512];
    int split = blockIdx.x, b = blockIdx.y, tid = threadIdx.x;
    int t0 = split * 128;
    const float* h2 = ws + OFF_H2;
    if (tid < 128) s_h2[tid] = h2[b * 128 + tid];
    __syncthreads();

    int wave = tid >> 6, lane = tid & 63;
    int lb = lens[b];
    float hx = s_h2[lane * 2], hy = s_h2[lane * 2 + 1];

    // energies for 32 rows per wave
    for (int i = 0; i < 32; ++i) {
        int r = wave * 32 + i;
        int tt = t0 + r;
        float2 kv = *(const float2*)(keys + (size_t)tt * 16384 + b * 128 + lane * 2);
        float p = kv.x * hx + kv.y * hy;
        p += __shfl_down(p, 32);
        p += __shfl_down(p, 16);
        p += __shfl_down(p, 8);
        p += __shfl_down(p, 4);
        p += __shfl_down(p, 2);
        p += __shfl_down(p, 1);
        if (lane == 0) s_e[r] = (tt >= lb) ? -1e9f : p;
    }
    __syncthreads();

    // local max over 128 (one wave)
    if (tid < 64) {
        float m = fmaxf(s_e[tid], s_e[tid + 64]);
        m = fmaxf(m, __shfl_down(m, 32));
        m = fmaxf(m, __shfl_down(m, 16));
        m = fmaxf(m, __shfl_down(m, 8));
        m = fmaxf(m, __shfl_down(m, 4));
        m = fmaxf(m, __shfl_down(m, 2));
        m = fmaxf(m, __shfl_down(m, 1));
        if (tid == 0) s_m[0] = m;
    }
    __syncthreads();
    float m = s_m[0];
    if (tid < 128) s_e[tid] = __expf(s_e[tid] - m);
    __syncthreads();
    if (tid < 64) {
        float ss = s_e[tid] + s_e[tid + 64];
        ss += __shfl_down(ss, 32);
        ss += __shfl_down(ss, 16);
        ss += __shfl_down(ss, 8);
        ss += __shfl_down(ss, 4);
        ss += __shfl_down(ss, 2);
        ss += __shfl_down(ss, 1);
        if (tid == 0) {
            ws[OFF_AM + b * NSPLIT + split] = m;
            ws[OFF_AS + b * NSPLIT + split] = ss;
        }
    }

    // partial ctx
    float ax = 0.f, ay = 0.f;
    for (int i = 0; i < 32; ++i) {
        int r = wave * 32 + i;
        int tt = t0 + r;
        float2 vv = *(const float2*)(values + (size_t)tt * 16384 + b * 128 + lane * 2);
        float a = s_e[r];
        ax += a * vv.x; ay += a * vv.y;
    }
    s_cp[wave * 128 + lane * 2]     = ax;
    s_cp[wave * 128 + lane * 2 + 1] = ay;
    __syncthreads();
    if (tid < 128) {
        float c_ = s_cp[tid] + s_cp[128 + tid] + s_cp[256 + tid] + s_cp[384 + tid];
        ws[OFF_AP + ((size_t)b * NSPLIT + split) * 128 + tid] = c_;
    }
}

// Attention pass 2: combine 16 partials per b; write ctx + stage next x1.
__global__ __launch_bounds__(384) void attn2_kernel(
    const int* __restrict__ text, const float* __restrict__ emb,
    float* __restrict__ ws, int t)
{
    __shared__ float s_m16[NSPLIT];
    __shared__ float s_s16[NSPLIT];
    int b = blockIdx.x, tid = threadIdx.x;
    if (tid < NSPLIT) {
        s_m16[tid] = ws[OFF_AM + b * NSPLIT + tid];
        s_s16[tid] = ws[OFF_AS + b * NSPLIT + tid];
    }
    __syncthreads();
    if (tid < 128) {
        float M = -3.4e38f;
        #pragma unroll
        for (int i = 0; i < NSPLIT; ++i) M = fmaxf(M, s_m16[i]);
        float Tsum = 0.f, c_ = 0.f;
        #pragma unroll
        for (int i = 0; i < NSPLIT; ++i) {
            float w = __expf(s_m16[i] - M);
            Tsum += s_s16[i] * w;
            c_ += w * ws[OFF_AP + ((size_t)b * NSPLIT + i) * 128 + tid];
        }
        c_ /= Tsum;
        ws[OFF_CTX + b * 128 + tid] = c_;
        ws[OFF_X1U + b * K1 + HID + tid] = c_;
    } else if (t + 1 < TDEC) {
        int k = tid - 128;                     // 0..255
        ws[OFF_X1U + b * K1 + k] = emb[text[b * TDEC + t + 1] * HID + k];
    }
}

// Output projection: [h2|ctx] @ WlinT + blin -> out[b][t][:]
__global__ __launch_bounds__(256) void pred_kernel(
    const float* __restrict__ ws, const float* __restrict__ blin,
    float* __restrict__ out, int t)
{
    const float* WlinT = ws + OFF_WLT;
    const float* h2  = ws + OFF_H2;
    const float* ctx = ws + OFF_CTX;
    int T = blockIdx.x * 256 + threadIdx.x;    // 32768
    int n = T & 1023, bq = T >> 10;
    if (n >= VOC) return;
    float bl = blin[n];
    float a0 = bl, a1 = bl, a2 = bl, a3 = bl;
    const float* xA = h2  + bq * 4 * 128;
    const float* xB = ctx + bq * 4 * 128;
    for (int k = 0; k < 128; ++k) {
        float w = WlinT[k * NPAD + n];
        a0 += xA[k] * w; a1 += xA[128 + k] * w; a2 += xA[256 + k] * w; a3 += xA[384 + k] * w;
    }
    for (int k = 0; k < 128; ++k) {
        float w = WlinT[(128 + k) * NPAD + n];
        a0 += xB[k] * w; a1 += xB[128 + k] * w; a2 += xB[256 + k] * w; a3 += xB[384 + k] * w;
    }
    size_t o = ((size_t)(bq * 4) * TDEC + t) * VOC + n;
    out[o]                          = a0;
    out[o + (size_t)TDEC * VOC]     = a1;
    out[o + 2 * (size_t)TDEC * VOC] = a2;
    out[o + 3 * (size_t)TDEC * VOC] = a3;
}

extern "C" void kernel_launch(void* const* d_in, const int* in_sizes, int n_in,
                              void* d_out, int out_size, void* d_ws, size_t ws_size,
                              hipStream_t stream)
{
    const float* keys   = (const float*)d_in[0];
    const float* values = (const float*)d_in[1];
    const int*   lens   = (const int*)d_in[2];
    const int*   text   = (const int*)d_in[3];
    const float* emb    = (const float*)d_in[4];
    const float* Wih1   = (const float*)d_in[5];
    const float* Whh1   = (const float*)d_in[6];
    const float* bih1   = (const float*)d_in[7];
    const float* bhh1   = (const float*)d_in[8];
    const float* Wih2   = (const float*)d_in[9];
    const float* Whh2   = (const float*)d_in[10];
    const float* bih2   = (const float*)d_in[11];
    const float* bhh2   = (const float*)d_in[12];
    const float* Wlin   = (const float*)d_in[13];
    const float* blin   = (const float*)d_in[14];
    float* ws  = (float*)d_ws;
    float* out = (float*)d_out;

    prep_kernel<<<PREP_ELEMS / 256, 256, 0, stream>>>(
        Wih1, Whh1, bih1, bhh1, Wih2, Whh2, bih2, bhh2, Wlin, emb, text, ws);

    for (int t = 0; t < TDEC; ++t) {
        l1A_kernel<<<256, 256, 0, stream>>>(ws);
        l1B_kernel<<<256, 256, 0, stream>>>(ws);
        l2A_kernel<<<64, 256, 0, stream>>>(ws);
        l2B_kernel<<<64, 256, 0, stream>>>(ws);
        attn1_kernel<<<dim3(NSPLIT, BSZ), 256, 0, stream>>>(keys, values, lens, ws);
        attn2_kernel<<<128, 384, 0, stream>>>(text, emb, ws, t);
        pred_kernel<<<128, 256, 0, stream>>>(ws, blin, out, t);
    }
}